// Round 3
// baseline (14261.343 us; speedup 1.0000x reference)
//
#include <hip/hip_runtime.h>

// TimeLSTM on MI355X (gfx950). B=64,S=1024,D=128,H=256.
// Scan: 64 blocks x 512 threads, 1 block/CU (8 waves), L2-stream-bound.
// ROUND-8: rounds 5-7 proved the allocator caps this kernel at 128 ARCH
// VGPRs (volatile-pinning 176 regs => scratch spills, 7.8ms). Hypothesis:
// gfx90a-style arch/acc split — at 2 waves/EU each wave gets 256 unified
// regs but only 128 as arch VGPRs; the other 128 are AGPRs this kernel
// never used. FIX: stash the 32 rowA weight chunks (128 dwords/thread) in
// AGPRs explicitly via v_accvgpr_write_b32 (volatile, once) and read them
// per-step with v_accvgpr_read_b32 (full-rate VALU). This removes 32 of
// the 61 streamed slots without touching the arch-VGPR working set.
// Partition per thread (80 chunks): 32 AGPR (rowA 0..31, 128 AGPRs) +
// 19 LDS (rowB 0..18, 159.7 KB) + 29 streamed from L2 (rowB 19..31 +
// W_d 0..15 = 238 KB/step/CU, 4-deep rolling pipeline).

#define B_ 64
#define S_ 1024
#define D_ 128
#define H_ 256
#define FH_ 1024
#define SMEM_BYTES (4096 + 19 * 512 * 16)   // 159744 <= 160 KiB

typedef _Float16 half2_t __attribute__((ext_vector_type(2)));
typedef _Float16 half4_t __attribute__((ext_vector_type(4)));
typedef _Float16 half8_t __attribute__((ext_vector_type(8)));
typedef float    f32x4   __attribute__((ext_vector_type(4)));

union HW { half8_t v; half2_t p[4]; };
union F4H8 { f32x4 f; half8_t h; };

__device__ inline float dot2acc(half2_t a, half2_t b, float c) {
#if __has_builtin(__builtin_amdgcn_fdot2)
    return __builtin_amdgcn_fdot2(a, b, c, false);
#else
    return c + (float)a[0] * (float)b[0] + (float)a[1] * (float)b[1];
#endif
}

__device__ inline float dot8acc(half8_t a, half8_t b, float c) {
    HW ua; ua.v = a;
    HW ub; ub.v = b;
    c = dot2acc(ua.p[0], ub.p[0], c);
    c = dot2acc(ua.p[1], ub.p[1], c);
    c = dot2acc(ua.p[2], ub.p[2], c);
    c = dot2acc(ua.p[3], ub.p[3], c);
    return c;
}

// Read one 16B weight chunk back from 4 AGPRs (full-rate VALU moves).
__device__ inline half8_t ag_read(const float (&a4)[4]) {
    F4H8 u;
    asm volatile("v_accvgpr_read_b32 %0, %1" : "=v"(u.f[0]) : "a"(a4[0]));
    asm volatile("v_accvgpr_read_b32 %0, %1" : "=v"(u.f[1]) : "a"(a4[1]));
    asm volatile("v_accvgpr_read_b32 %0, %1" : "=v"(u.f[2]) : "a"(a4[2]));
    asm volatile("v_accvgpr_read_b32 %0, %1" : "=v"(u.f[3]) : "a"(a4[3]));
    return u.h;
}

__device__ inline float sigmoid_f(float x) { return 1.f / (1.f + __expf(-x)); }
__device__ inline float tanh_f(float x)    { return 1.f - 2.f / (__expf(2.f * x) + 1.f); }

// ---------------------------------------------------------------------------
// Pack (unchanged, validated). WX slot-major: WX[slot][512][8], slot in [0,80):
//   slot<32 : rowA chunks (f for t<256, o for t>=256)
//   32..63  : rowB chunks (i / c~)
//   64..79  : W_d[e] chunk (slot-64) + hi*16  (cols 0..127 / 128..255)
// ---------------------------------------------------------------------------
__global__ __launch_bounds__(256) void pack_kernel(
    const float* __restrict__ Wall, const float* __restrict__ Wd,
    const float* __restrict__ Uall, const float* __restrict__ ts,
    _Float16* __restrict__ WX, _Float16* __restrict__ U16,
    float* __restrict__ decay)
{
    int idx = blockIdx.x * 256 + threadIdx.x;
    if (idx < 40960) {
        int slot = idx >> 9, t = idx & 511;
        int e = t & 255, hi = t >> 8;
        int row, ch;
        if (slot < 32)      { row = (hi ? 512 : 0)   + e; ch = slot; }
        else if (slot < 64) { row = (hi ? 768 : 256) + e; ch = slot - 32; }
        else                { row = 1024 + e;             ch = (slot - 64) + (hi ? 16 : 0); }
        const float* src = (row < 1024) ? (Wall + (size_t)row * H_ + ch * 8)
                                        : (Wd + (size_t)(row - 1024) * H_ + ch * 8);
        _Float16* dst = WX + ((size_t)slot * 512 + t) * 8;
        #pragma unroll
        for (int j = 0; j < 8; j++) dst[j] = (_Float16)src[j];
    } else if (idx < 40960 + 131072) {
        int i = idx - 40960;
        U16[i] = (_Float16)Uall[i];
    } else if (idx < 40960 + 131072 + 65536) {
        int i = idx - 172032;
        int bb = i >> 10, s = i & 1023;
        float d = 1.f;
        if (s > 0) {
            float dt = ts[bb * S_ + s] - ts[bb * S_ + s - 1];
            dt = fmaxf(dt, 1e-6f);
            d = 1.f / logf(2.718281828459045f + dt);
        }
        decay[i] = d;
    }
}

// ---------------------------------------------------------------------------
// u GEMM via MFMA 16x16x32 f16 (unchanged, validated). Stores u
// gate-interleaved: u16[row][e*4+g], g in {f,i,o,c~}.
// ---------------------------------------------------------------------------
__global__ __launch_bounds__(256) void u_gemm_mfma(
    const float* __restrict__ x, const _Float16* __restrict__ U16,
    const float* __restrict__ Ub, _Float16* __restrict__ u16)
{
    int wave = threadIdx.x >> 6, lane = threadIdx.x & 63;
    size_t row0 = (size_t)blockIdx.x * 64 + wave * 16;
    int n0 = blockIdx.y * 256;
    int am = lane & 15;
    int ak = (lane >> 4) * 8;
    const float* xr = x + (row0 + am) * D_ + ak;

    f32x4 acc[16];
    #pragma unroll
    for (int nt = 0; nt < 16; nt++) acc[nt] = (f32x4){0.f, 0.f, 0.f, 0.f};

    #pragma unroll
    for (int kc = 0; kc < 4; kc++) {
        half8_t a;
        #pragma unroll
        for (int e = 0; e < 8; e++) a[e] = (_Float16)xr[kc * 32 + e];
        #pragma unroll
        for (int nt = 0; nt < 16; nt++) {
            half8_t bfr = *(const half8_t*)(U16 + (size_t)(n0 + nt * 16 + am) * D_ + kc * 32 + ak);
            acc[nt] = __builtin_amdgcn_mfma_f32_16x16x32_f16(a, bfr, acc[nt], 0, 0, 0);
        }
    }

    int cr = (lane >> 4) * 4;
    #pragma unroll
    for (int nt = 0; nt < 16; nt++) {
        int col = n0 + nt * 16 + am;
        float bias = Ub[col];
        int e = col & 255, g = col >> 8;
        #pragma unroll
        for (int i = 0; i < 4; i++) {
            u16[(row0 + cr + i) * (size_t)FH_ + e * 4 + g] = (_Float16)(acc[nt][i] + bias);
        }
    }
}

// ---------------------------------------------------------------------------
// Scan.
// ---------------------------------------------------------------------------
__global__ void __launch_bounds__(512) __attribute__((amdgpu_waves_per_eu(2, 2)))
scan_kernel(
    const _Float16* __restrict__ u16, const _Float16* __restrict__ WX,
    const float* __restrict__ Wb, const float* __restrict__ Wdb,
    const float* __restrict__ decay, float* __restrict__ out)
{
    int b = blockIdx.x, t = threadIdx.x;
    int e = t & 255, hi = t >> 8;

    extern __shared__ __align__(16) char smem[];
    _Float16* h16  = (_Float16*)smem;                 // 512 B
    _Float16* c16  = (_Float16*)(smem + 512);         // 512 B
    float*    po_s = (float*)(smem + 1024);           // 1 KB
    float*    pc_s = (float*)(smem + 2048);           // 1 KB
    float*    adh_s= (float*)(smem + 3072);           // 1 KB
    half8_t*  wl   = (half8_t*)(smem + 4096);         // 19 chunks x 512 thr

    const half8_t* __restrict__ WX8 = (const half8_t*)WX;

    // ---- LDS weights: slots 32..50 (rowB chunks 0..18) ----
    #pragma unroll
    for (int j = 0; j < 19; j++) wl[(size_t)j * 512 + t] = WX8[(size_t)(32 + j) * 512 + t];

    // ---- AGPR stash: slots 0..31 (rowA chunks) -> 128 AGPRs/thread.
    //      Volatile writes cannot be rematerialized; the values live in the
    //      accum half of the register file the arch-VGPR allocator ignores. ----
    float agA[32][4];
    #pragma unroll
    for (int cc = 0; cc < 32; cc++) {
        F4H8 u; u.h = WX8[(size_t)cc * 512 + t];
        asm volatile("v_accvgpr_write_b32 %0, %1" : "=a"(agA[cc][0]) : "v"(u.f[0]));
        asm volatile("v_accvgpr_write_b32 %0, %1" : "=a"(agA[cc][1]) : "v"(u.f[1]));
        asm volatile("v_accvgpr_write_b32 %0, %1" : "=a"(agA[cc][2]) : "v"(u.f[2]));
        asm volatile("v_accvgpr_write_b32 %0, %1" : "=a"(agA[cc][3]) : "v"(u.f[3]));
    }

    float bA = Wb[hi * 512 + e];           // f / o bias
    float bB = Wb[hi * 512 + 256 + e];     // i / c~ bias
    float wdbt = Wdb[e];

    if (hi == 0) { h16[e] = (_Float16)0.f; c16[e] = (_Float16)0.f; }
    float c_reg = 0.f, hn = 0.f;
    __syncthreads();

    const _Float16* __restrict__ ub   = u16 + (size_t)b * S_ * FH_;
    const float*    __restrict__ db   = decay + (size_t)b * S_;
    float*          __restrict__ outb = out + (size_t)b * S_ * H_;
    // streamed slots 51..79: rowB chunks 19..31 (13) + W_d chunks 0..15 (16)
    const half8_t*  __restrict__ sp   = WX8 + (size_t)51 * 512 + t;

    const half8_t* hb8 = (const half8_t*)h16;
    const half8_t* cb8 = (const half8_t*)c16 + hi * 16;

    for (int s = 0; s < S_; s++) {
        half2_t u2 = *(const half2_t*)(ub + (size_t)s * FH_ + e * 4 + hi * 2);

        // rolling 4-deep stream pipeline over 29 chunks
        half8_t sw[4];
        #pragma unroll
        for (int j = 0; j < 4; j++) sw[j] = sp[(size_t)j * 512];

        float aA = 0.f, aB = 0.f, aD = 0.f;

        // rowA (AGPR) + rowB (LDS) chunks 0..18
        #pragma unroll
        for (int cc = 0; cc < 19; cc++) {
            half8_t h8 = hb8[cc];
            aA = dot8acc(h8, ag_read(agA[cc]), aA);
            aB = dot8acc(h8, wl[(size_t)cc * 512 + t], aB);
        }
        // rowA (AGPR) chunks 19..31
        #pragma unroll
        for (int cc = 19; cc < 32; cc++) {
            aA = dot8acc(hb8[cc], ag_read(agA[cc]), aA);
        }
        // streamed: rowB 19..31 (with h), then W_d 0..15 (with c)
        #pragma unroll
        for (int i = 0; i < 29; i++) {
            half8_t w = sw[i & 3];
            if (i + 4 < 29) sw[i & 3] = sp[(size_t)(i + 4) * 512];
            if (i < 13) aB = dot8acc(hb8[19 + i], w, aB);
            else        aD = dot8acc(cb8[i - 13], w, aD);
        }

        float pA = aA + bA + (float)u2[0];
        float pB = aB + bB + (float)u2[1];

        if (hi) {
            po_s[e]  = pA;
            pc_s[e]  = pB;
            adh_s[e] = aD;
        }
        __syncthreads();
        if (!hi) {
            float dly  = db[s];
            float cs   = tanh_f(aD + adh_s[e] + wdbt);
            float cadj = (c_reg - cs) + cs * dly;
            float cn   = sigmoid_f(pA) * cadj + sigmoid_f(pB) * tanh_f(pc_s[e]);
            hn = sigmoid_f(po_s[e]) * tanh_f(cn);
            c_reg = cn;
            outb[(size_t)s * H_ + e] = hn;
            h16[e] = (_Float16)hn;
            c16[e] = (_Float16)cn;
        }
        __syncthreads();
    }

    if (!hi) {
        out[(size_t)B_ * S_ * H_ + (size_t)b * H_ + e] = hn;
        out[(size_t)B_ * S_ * H_ + (size_t)B_ * H_ + (size_t)b * H_ + e] = c_reg;
    }
}

// ---------------------------------------------------------------------------
extern "C" void kernel_launch(void* const* d_in, const int* in_sizes, int n_in,
                              void* d_out, int out_size, void* d_ws, size_t ws_size,
                              hipStream_t stream) {
    const float* inputs     = (const float*)d_in[0];   // [B,S,D]
    const float* timestamps = (const float*)d_in[1];   // [B,S]
    const float* W_all_w    = (const float*)d_in[2];   // [4H,H]
    const float* W_all_b    = (const float*)d_in[3];   // [4H]
    const float* U_all_w    = (const float*)d_in[4];   // [4H,D]
    const float* U_all_b    = (const float*)d_in[5];   // [4H]
    const float* W_d_w      = (const float*)d_in[6];   // [H,H]
    const float* W_d_b      = (const float*)d_in[7];   // [H]
    float* out = (float*)d_out;

    char* p = (char*)d_ws;
    _Float16* u16 = (_Float16*)p;   p += (size_t)B_ * S_ * FH_ * 2;   // 128 MiB
    _Float16* WX  = (_Float16*)p;   p += (size_t)80 * 512 * 8 * 2;    // 640 KiB
    _Float16* U16 = (_Float16*)p;   p += (size_t)FH_ * D_ * 2;        // 256 KiB
    float*    dec = (float*)p;                                         // 256 KiB

    (void)hipFuncSetAttribute((const void*)scan_kernel,
                              hipFuncAttributeMaxDynamicSharedMemorySize,
                              SMEM_BYTES);

    pack_kernel<<<dim3(928), dim3(256), 0, stream>>>(
        W_all_w, W_d_w, U_all_w, timestamps, WX, U16, dec);
    u_gemm_mfma<<<dim3(1024, 4), dim3(256), 0, stream>>>(
        inputs, U16, U_all_b, u16);
    scan_kernel<<<dim3(B_), dim3(512), SMEM_BYTES, stream>>>(
        u16, WX, W_all_b, W_d_b, dec, out);
}

// Round 4
// 7836.144 us; speedup vs baseline: 1.8199x; 1.8199x over previous
//
#include <hip/hip_runtime.h>

// TimeLSTM on MI355X (gfx950). B=64,S=1024,D=128,H=256.
// Scan: 64 blocks x 512 threads, 1 block/CU (LDS-capped), 2 waves/EU.
// ROUND-9: rounds 5-8 established (a) volatile-pin DOES keep values live,
// (b) the backend budgeted 128 VGPRs *total* (4 waves/EU default — the
// amdgpu_waves_per_eu(2,2) attribute never took effect; with extern-shared
// LDS the compiler can't see the 156KB that already caps us at 2 waves/EU),
// (c) gfx950 AGPRs share the SAME unified file — no extra space there.
// FIX: __launch_bounds__(512, 2) — HIP's documented knob where the 2nd arg
// is MIN WAVES PER EU, setting the allocator cap to 512/2 = 256 VGPRs/wave.
// Physical occupancy is unchanged (1 block/CU via LDS), so this is free.
// Partition per thread (80 chunks): 44 pinned VGPR (176 regs: rowA 0..31 +
// rowB 0..11) + 19 LDS (slots 44..62, 159.7 KB dynamic) + 17 streamed from
// L2 (slots 63..79 = rowB 31 + W_d 0..15, 139 KB/step/CU, 4-deep pipeline).

#define B_ 64
#define S_ 1024
#define D_ 128
#define H_ 256
#define FH_ 1024
#define SMEM_BYTES (4096 + 19 * 512 * 16)   // 159744 <= 160 KiB

typedef _Float16 half2_t __attribute__((ext_vector_type(2)));
typedef _Float16 half4_t __attribute__((ext_vector_type(4)));
typedef _Float16 half8_t __attribute__((ext_vector_type(8)));
typedef float    f32x4   __attribute__((ext_vector_type(4)));

union HW { half8_t v; half2_t p[4]; };

__device__ inline float dot2acc(half2_t a, half2_t b, float c) {
#if __has_builtin(__builtin_amdgcn_fdot2)
    return __builtin_amdgcn_fdot2(a, b, c, false);
#else
    return c + (float)a[0] * (float)b[0] + (float)a[1] * (float)b[1];
#endif
}

__device__ inline float dot8acc(half8_t a, half8_t b, float c) {
    HW ua; ua.v = a;
    HW ub; ub.v = b;
    c = dot2acc(ua.p[0], ub.p[0], c);
    c = dot2acc(ua.p[1], ub.p[1], c);
    c = dot2acc(ua.p[2], ub.p[2], c);
    c = dot2acc(ua.p[3], ub.p[3], c);
    return c;
}

__device__ inline float sigmoid_f(float x) { return 1.f / (1.f + __expf(-x)); }
__device__ inline float tanh_f(float x)    { return 1.f - 2.f / (__expf(2.f * x) + 1.f); }

// ---------------------------------------------------------------------------
// Pack (unchanged, validated). WX slot-major: WX[slot][512][8], slot in [0,80):
//   slot<32 : rowA chunks (f for t<256, o for t>=256)
//   32..63  : rowB chunks (i / c~)
//   64..79  : W_d[e] chunk (slot-64) + hi*16  (cols 0..127 / 128..255)
// ---------------------------------------------------------------------------
__global__ __launch_bounds__(256) void pack_kernel(
    const float* __restrict__ Wall, const float* __restrict__ Wd,
    const float* __restrict__ Uall, const float* __restrict__ ts,
    _Float16* __restrict__ WX, _Float16* __restrict__ U16,
    float* __restrict__ decay)
{
    int idx = blockIdx.x * 256 + threadIdx.x;
    if (idx < 40960) {
        int slot = idx >> 9, t = idx & 511;
        int e = t & 255, hi = t >> 8;
        int row, ch;
        if (slot < 32)      { row = (hi ? 512 : 0)   + e; ch = slot; }
        else if (slot < 64) { row = (hi ? 768 : 256) + e; ch = slot - 32; }
        else                { row = 1024 + e;             ch = (slot - 64) + (hi ? 16 : 0); }
        const float* src = (row < 1024) ? (Wall + (size_t)row * H_ + ch * 8)
                                        : (Wd + (size_t)(row - 1024) * H_ + ch * 8);
        _Float16* dst = WX + ((size_t)slot * 512 + t) * 8;
        #pragma unroll
        for (int j = 0; j < 8; j++) dst[j] = (_Float16)src[j];
    } else if (idx < 40960 + 131072) {
        int i = idx - 40960;
        U16[i] = (_Float16)Uall[i];
    } else if (idx < 40960 + 131072 + 65536) {
        int i = idx - 172032;
        int bb = i >> 10, s = i & 1023;
        float d = 1.f;
        if (s > 0) {
            float dt = ts[bb * S_ + s] - ts[bb * S_ + s - 1];
            dt = fmaxf(dt, 1e-6f);
            d = 1.f / logf(2.718281828459045f + dt);
        }
        decay[i] = d;
    }
}

// ---------------------------------------------------------------------------
// u GEMM via MFMA 16x16x32 f16 (unchanged, validated). Stores u
// gate-interleaved: u16[row][e*4+g], g in {f,i,o,c~}.
// ---------------------------------------------------------------------------
__global__ __launch_bounds__(256) void u_gemm_mfma(
    const float* __restrict__ x, const _Float16* __restrict__ U16,
    const float* __restrict__ Ub, _Float16* __restrict__ u16)
{
    int wave = threadIdx.x >> 6, lane = threadIdx.x & 63;
    size_t row0 = (size_t)blockIdx.x * 64 + wave * 16;
    int n0 = blockIdx.y * 256;
    int am = lane & 15;
    int ak = (lane >> 4) * 8;
    const float* xr = x + (row0 + am) * D_ + ak;

    f32x4 acc[16];
    #pragma unroll
    for (int nt = 0; nt < 16; nt++) acc[nt] = (f32x4){0.f, 0.f, 0.f, 0.f};

    #pragma unroll
    for (int kc = 0; kc < 4; kc++) {
        half8_t a;
        #pragma unroll
        for (int e = 0; e < 8; e++) a[e] = (_Float16)xr[kc * 32 + e];
        #pragma unroll
        for (int nt = 0; nt < 16; nt++) {
            half8_t bfr = *(const half8_t*)(U16 + (size_t)(n0 + nt * 16 + am) * D_ + kc * 32 + ak);
            acc[nt] = __builtin_amdgcn_mfma_f32_16x16x32_f16(a, bfr, acc[nt], 0, 0, 0);
        }
    }

    int cr = (lane >> 4) * 4;
    #pragma unroll
    for (int nt = 0; nt < 16; nt++) {
        int col = n0 + nt * 16 + am;
        float bias = Ub[col];
        int e = col & 255, g = col >> 8;
        #pragma unroll
        for (int i = 0; i < 4; i++) {
            u16[(row0 + cr + i) * (size_t)FH_ + e * 4 + g] = (_Float16)(acc[nt][i] + bias);
        }
    }
}

// ---------------------------------------------------------------------------
// Scan.
// ---------------------------------------------------------------------------
__global__ void __launch_bounds__(512, 2)
scan_kernel(
    const _Float16* __restrict__ u16, const _Float16* __restrict__ WX,
    const float* __restrict__ Wb, const float* __restrict__ Wdb,
    const float* __restrict__ decay, float* __restrict__ out)
{
    int b = blockIdx.x, t = threadIdx.x;
    int e = t & 255, hi = t >> 8;

    extern __shared__ __align__(16) char smem[];
    _Float16* h16  = (_Float16*)smem;                 // 512 B
    _Float16* c16  = (_Float16*)(smem + 512);         // 512 B
    float*    po_s = (float*)(smem + 1024);           // 1 KB
    float*    pc_s = (float*)(smem + 2048);           // 1 KB
    float*    adh_s= (float*)(smem + 3072);           // 1 KB
    half8_t*  wl   = (half8_t*)(smem + 4096);         // 19 chunks x 512 thr

    const half8_t* __restrict__ WX8 = (const half8_t*)WX;

    // ---- LDS weights: slots 44..62 (rowB chunks 12..30) ----
    #pragma unroll
    for (int j = 0; j < 19; j++) wl[(size_t)j * 512 + t] = WX8[(size_t)(44 + j) * 512 + t];

    // ---- pinned weights: slots 0..43 (rowA 0..31 + rowB 0..11) ----
    half8_t wA[32], wB[12];
    #pragma unroll
    for (int cc = 0; cc < 32; cc++) wA[cc] = WX8[(size_t)cc * 512 + t];
    #pragma unroll
    for (int j = 0; j < 12; j++)  wB[j] = WX8[(size_t)(32 + j) * 512 + t];

    // ---- PIN: VOLATILE empty asm — cannot be duplicated or rematerialized,
    //      so the 176 regs stay live across the in-loop barriers. With the
    //      256-VGPR budget from __launch_bounds__(512,2) this fits. ----
    #pragma unroll
    for (int cc = 0; cc < 32; cc++) asm volatile("" : "+v"(wA[cc]));
    #pragma unroll
    for (int j = 0; j < 12; j++)  asm volatile("" : "+v"(wB[j]));

    float bA = Wb[hi * 512 + e];           // f / o bias
    float bB = Wb[hi * 512 + 256 + e];     // i / c~ bias
    float wdbt = Wdb[e];

    if (hi == 0) { h16[e] = (_Float16)0.f; c16[e] = (_Float16)0.f; }
    float c_reg = 0.f, hn = 0.f;
    __syncthreads();

    const _Float16* __restrict__ ub   = u16 + (size_t)b * S_ * FH_;
    const float*    __restrict__ db   = decay + (size_t)b * S_;
    float*          __restrict__ outb = out + (size_t)b * S_ * H_;
    // streamed slots 63..79: rowB chunk 31 (1) + W_d chunks 0..15 (16)
    const half8_t*  __restrict__ sp   = WX8 + (size_t)63 * 512 + t;

    const half8_t* hb8 = (const half8_t*)h16;
    const half8_t* cb8 = (const half8_t*)c16 + hi * 16;

    for (int s = 0; s < S_; s++) {
        half2_t u2 = *(const half2_t*)(ub + (size_t)s * FH_ + e * 4 + hi * 2);

        // rolling 4-deep stream pipeline over 17 chunks
        half8_t sw[4];
        #pragma unroll
        for (int j = 0; j < 4; j++) sw[j] = sp[(size_t)j * 512];

        float aA = 0.f, aB = 0.f, aD = 0.f;

        // pinned-register dots (rowA 0..11 + rowB 0..11)
        #pragma unroll
        for (int cc = 0; cc < 12; cc++) {
            half8_t h8 = hb8[cc];
            aA = dot8acc(h8, wA[cc], aA);
            aB = dot8acc(h8, wB[cc], aB);
        }
        // rowA 12..30 + rowB(LDS) 12..30
        #pragma unroll
        for (int cc = 12; cc < 31; cc++) {
            half8_t h8 = hb8[cc];
            aA = dot8acc(h8, wA[cc], aA);
            aB = dot8acc(h8, wl[(size_t)(cc - 12) * 512 + t], aB);
        }
        // rowA chunk 31 (pinned); keep h31 for the streamed rowB-31 dot
        half8_t h31 = hb8[31];
        aA = dot8acc(h31, wA[31], aA);

        // streamed: rowB 31 (with h), then W_d 0..15 (with c)
        #pragma unroll
        for (int i = 0; i < 17; i++) {
            half8_t w = sw[i & 3];
            if (i + 4 < 17) sw[i & 3] = sp[(size_t)(i + 4) * 512];
            if (i == 0) aB = dot8acc(h31, w, aB);
            else        aD = dot8acc(cb8[i - 1], w, aD);
        }

        float pA = aA + bA + (float)u2[0];
        float pB = aB + bB + (float)u2[1];

        if (hi) {
            po_s[e]  = pA;
            pc_s[e]  = pB;
            adh_s[e] = aD;
        }
        __syncthreads();
        if (!hi) {
            float dly  = db[s];
            float cs   = tanh_f(aD + adh_s[e] + wdbt);
            float cadj = (c_reg - cs) + cs * dly;
            float cn   = sigmoid_f(pA) * cadj + sigmoid_f(pB) * tanh_f(pc_s[e]);
            hn = sigmoid_f(po_s[e]) * tanh_f(cn);
            c_reg = cn;
            outb[(size_t)s * H_ + e] = hn;
            h16[e] = (_Float16)hn;
            c16[e] = (_Float16)cn;
        }
        __syncthreads();
    }

    if (!hi) {
        out[(size_t)B_ * S_ * H_ + (size_t)b * H_ + e] = hn;
        out[(size_t)B_ * S_ * H_ + (size_t)B_ * H_ + (size_t)b * H_ + e] = c_reg;
    }
}

// ---------------------------------------------------------------------------
extern "C" void kernel_launch(void* const* d_in, const int* in_sizes, int n_in,
                              void* d_out, int out_size, void* d_ws, size_t ws_size,
                              hipStream_t stream) {
    const float* inputs     = (const float*)d_in[0];   // [B,S,D]
    const float* timestamps = (const float*)d_in[1];   // [B,S]
    const float* W_all_w    = (const float*)d_in[2];   // [4H,H]
    const float* W_all_b    = (const float*)d_in[3];   // [4H]
    const float* U_all_w    = (const float*)d_in[4];   // [4H,D]
    const float* U_all_b    = (const float*)d_in[5];   // [4H]
    const float* W_d_w      = (const float*)d_in[6];   // [H,H]
    const float* W_d_b      = (const float*)d_in[7];   // [H]
    float* out = (float*)d_out;

    char* p = (char*)d_ws;
    _Float16* u16 = (_Float16*)p;   p += (size_t)B_ * S_ * FH_ * 2;   // 128 MiB
    _Float16* WX  = (_Float16*)p;   p += (size_t)80 * 512 * 8 * 2;    // 640 KiB
    _Float16* U16 = (_Float16*)p;   p += (size_t)FH_ * D_ * 2;        // 256 KiB
    float*    dec = (float*)p;                                         // 256 KiB

    (void)hipFuncSetAttribute((const void*)scan_kernel,
                              hipFuncAttributeMaxDynamicSharedMemorySize,
                              SMEM_BYTES);

    pack_kernel<<<dim3(928), dim3(256), 0, stream>>>(
        W_all_w, W_d_w, U_all_w, timestamps, WX, U16, dec);
    u_gemm_mfma<<<dim3(1024, 4), dim3(256), 0, stream>>>(
        inputs, U16, U_all_b, u16);
    scan_kernel<<<dim3(B_), dim3(512), SMEM_BYTES, stream>>>(
        u16, WX, W_all_b, W_d_b, dec, out);
}

// Round 5
// 4532.842 us; speedup vs baseline: 3.1462x; 1.7287x over previous
//
#include <hip/hip_runtime.h>

// TimeLSTM on MI355X (gfx950). B=64,S=1024,D=128,H=256.
// ROUND-10: rounds 5-9 proved the backend grants this kernel 128 VGPRs/wave
// no matter how waves-per-eu is spelled (attr and launch_bounds(512,2) both:
// VGPR_Count=128; 176-reg pin => scratch spill, 7.8ms). Accept 128 as fact.
// At 512 thr/block (2 waves/SIMD x 128) HALF the 512-reg/SIMD file is idle.
// FIX: 1024-thread scan block (16 waves = 4/SIMD x 128 = full file) so the
// same 128 budget addresses 512KB/CU of registers. Thread t owns gate-row t
// (g=t>>8 wave-uniform, e=t&255): 32 gate chunks + 8 W_d-slice chunks.
// Partition per thread (40 chunks): 16 pinned VGPR (64 regs, 256KB/CU) +
// 9 LDS slots (144KB) + 15 streamed from L2 (240KB/step/CU vs 500 before).
// h/c broadcast via per-lane slice + compile-time readlane (VALU pipe, SGPR
// operands feed v_dot2 directly) instead of 40 broadcast LDS reads/wave.
// Gate combine: LDS pg/pd reduce by threads t<256 (c state lives there).

#define B_ 64
#define S_ 1024
#define D_ 128
#define H_ 256
#define FH_ 1024
// h(512) c(512) pg(4KB) pd(4KB) wl(9*16KB)
#define SMEM_BYTES (1024 + 4096 + 4096 + 9 * 1024 * 16)   // 156672 <= 160 KiB

typedef _Float16 half2_t __attribute__((ext_vector_type(2)));
typedef _Float16 half8_t __attribute__((ext_vector_type(8)));
typedef float    f32x4   __attribute__((ext_vector_type(4)));

union HW { half8_t v; half2_t p[4]; };
union U32H2 { unsigned int u; half2_t h; };

__device__ inline float dot2acc(half2_t a, half2_t b, float c) {
#if __has_builtin(__builtin_amdgcn_fdot2)
    return __builtin_amdgcn_fdot2(a, b, c, false);
#else
    return c + (float)a[0] * (float)b[0] + (float)a[1] * (float)b[1];
#endif
}

__device__ inline float sigmoid_f(float x) { return 1.f / (1.f + __expf(-x)); }
__device__ inline float tanh_f(float x)    { return 1.f - 2.f / (__expf(2.f * x) + 1.f); }

// ---------------------------------------------------------------------------
// Pack. WX slot-major: WX[slot][1024][8], slot in [0,40):
//   slot<32 : gate chunk — WX[c][t] = W_all[row t][c*8 .. c*8+8)
//   32..39  : W_d slice  — WX[32+k][(g<<8)|e] = W_d[e][g*64 + k*8 .. +8)
// ---------------------------------------------------------------------------
__global__ __launch_bounds__(256) void pack_kernel(
    const float* __restrict__ Wall, const float* __restrict__ Wd,
    const float* __restrict__ Uall, const float* __restrict__ ts,
    _Float16* __restrict__ WX, _Float16* __restrict__ U16,
    float* __restrict__ decay)
{
    int idx = blockIdx.x * 256 + threadIdx.x;
    if (idx < 40960) {
        int slot = idx >> 10, t = idx & 1023;
        const float* src;
        if (slot < 32) {
            src = Wall + (size_t)t * H_ + slot * 8;
        } else {
            int e = t & 255, g = t >> 8, k = slot - 32;
            src = Wd + (size_t)e * H_ + g * 64 + k * 8;
        }
        _Float16* dst = WX + ((size_t)slot * 1024 + t) * 8;
        #pragma unroll
        for (int j = 0; j < 8; j++) dst[j] = (_Float16)src[j];
    } else if (idx < 40960 + 131072) {
        int i = idx - 40960;
        U16[i] = (_Float16)Uall[i];
    } else if (idx < 40960 + 131072 + 65536) {
        int i = idx - 172032;
        int bb = i >> 10, s = i & 1023;
        float d = 1.f;
        if (s > 0) {
            float dt = ts[bb * S_ + s] - ts[bb * S_ + s - 1];
            dt = fmaxf(dt, 1e-6f);
            d = 1.f / logf(2.718281828459045f + dt);
        }
        decay[i] = d;
    }
}

// ---------------------------------------------------------------------------
// u GEMM via MFMA 16x16x32 f16. Stores u PLAIN: u16[row][col], col = gate-row
// index in [0,1024) (f:0..255, i:256..511, o:512..767, c~:768..1023) — the
// scan's thread t reads u16[s][t] fully coalesced.
// ---------------------------------------------------------------------------
__global__ __launch_bounds__(256) void u_gemm_mfma(
    const float* __restrict__ x, const _Float16* __restrict__ U16,
    const float* __restrict__ Ub, _Float16* __restrict__ u16)
{
    int wave = threadIdx.x >> 6, lane = threadIdx.x & 63;
    size_t row0 = (size_t)blockIdx.x * 64 + wave * 16;
    int n0 = blockIdx.y * 256;
    int am = lane & 15;
    int ak = (lane >> 4) * 8;
    const float* xr = x + (row0 + am) * D_ + ak;

    f32x4 acc[16];
    #pragma unroll
    for (int nt = 0; nt < 16; nt++) acc[nt] = (f32x4){0.f, 0.f, 0.f, 0.f};

    #pragma unroll
    for (int kc = 0; kc < 4; kc++) {
        half8_t a;
        #pragma unroll
        for (int e = 0; e < 8; e++) a[e] = (_Float16)xr[kc * 32 + e];
        #pragma unroll
        for (int nt = 0; nt < 16; nt++) {
            half8_t bfr = *(const half8_t*)(U16 + (size_t)(n0 + nt * 16 + am) * D_ + kc * 32 + ak);
            acc[nt] = __builtin_amdgcn_mfma_f32_16x16x32_f16(a, bfr, acc[nt], 0, 0, 0);
        }
    }

    int cr = (lane >> 4) * 4;
    #pragma unroll
    for (int nt = 0; nt < 16; nt++) {
        int col = n0 + nt * 16 + am;
        float bias = Ub[col];
        #pragma unroll
        for (int i = 0; i < 4; i++) {
            u16[(row0 + cr + i) * (size_t)FH_ + col] = (_Float16)(acc[nt][i] + bias);
        }
    }
}

// ---------------------------------------------------------------------------
// Scan. 64 blocks x 1024 threads (16 waves, 4/SIMD, full 512-reg file at the
// 128/wave budget the backend insists on).
// ---------------------------------------------------------------------------
__global__ void __launch_bounds__(1024)
scan_kernel(
    const _Float16* __restrict__ u16, const _Float16* __restrict__ WX,
    const float* __restrict__ Wb, const float* __restrict__ Wdb,
    const float* __restrict__ decay, float* __restrict__ out)
{
    int b = blockIdx.x, t = threadIdx.x;
    int e = t & 255, g = t >> 8, lane = t & 63;

    extern __shared__ __align__(16) char smem[];
    _Float16* h16 = (_Float16*)smem;              // [256] fp16
    _Float16* c16 = (_Float16*)(smem + 512);      // [256] fp16
    float*    pg  = (float*)(smem + 1024);        // [1024] gate pre-acts
    float*    pd  = (float*)(smem + 5120);        // [1024] W_d partials
    half8_t*  wl  = (half8_t*)(smem + 9216);      // 9 slots x 1024 thr

    const half8_t* __restrict__ WX8 = (const half8_t*)WX;

    // ---- LDS weights: slots 16..24 (gate chunks 16..24) ----
    #pragma unroll
    for (int j = 0; j < 9; j++) wl[(size_t)j * 1024 + t] = WX8[(size_t)(16 + j) * 1024 + t];

    // ---- pinned weights: slots 0..15 (gate chunks 0..15), 64 VGPRs.
    //      Volatile pin (cannot be rematerialized); 64 + ~50 working < 128. ----
    half8_t wA[16];
    #pragma unroll
    for (int c = 0; c < 16; c++) wA[c] = WX8[(size_t)c * 1024 + t];
    #pragma unroll
    for (int c = 0; c < 16; c++) asm volatile("" : "+v"(wA[c]));

    float bA   = Wb[t];
    float wdbt = (t < 256) ? Wdb[e] : 0.f;

    if (t < 256) { h16[t] = (_Float16)0.f; c16[t] = (_Float16)0.f; }
    float c_reg = 0.f, hn = 0.f;
    __syncthreads();

    const _Float16* __restrict__ ub   = u16 + (size_t)b * S_ * FH_;
    const float*    __restrict__ db   = decay + (size_t)b * S_;
    float*          __restrict__ outb = out + (size_t)b * S_ * H_;
    // streamed slots 25..39: gate chunks 25..31 (7) + W_d slices 0..7 (8)
    const half8_t*  __restrict__ sp   = WX8 + (size_t)25 * 1024 + t;

    for (int s = 0; s < S_; s++) {
        float uval = (float)ub[(size_t)s * FH_ + t];

        // per-lane h/c slices (the ONLY LDS state reads; broadcast is readlane)
        uint2 hp = *(const uint2*)((const char*)h16 + 8 * lane);            // h[4l..4l+4)
        unsigned int cp = *(const unsigned int*)((const char*)c16 + 4 * ((g << 5) + (lane & 31)));

        // rolling 4-deep stream pipeline over 15 chunks
        half8_t sw[4];
        #pragma unroll
        for (int j = 0; j < 4; j++) sw[j] = sp[(size_t)j * 1024];

        float aA = 0.f, aD = 0.f;

        // gate-row dot: 32 chunks; h chunk c broadcast from lanes 2c, 2c+1
        #pragma unroll
        for (int c = 0; c < 32; c++) {
            U32H2 d0, d1, d2, d3;
            d0.u = __builtin_amdgcn_readlane(hp.x, 2 * c);
            d1.u = __builtin_amdgcn_readlane(hp.y, 2 * c);
            d2.u = __builtin_amdgcn_readlane(hp.x, 2 * c + 1);
            d3.u = __builtin_amdgcn_readlane(hp.y, 2 * c + 1);
            half8_t w;
            if (c < 16) {
                w = wA[c];
            } else if (c < 25) {
                w = wl[(size_t)(c - 16) * 1024 + t];
            } else {
                int i = c - 25;
                w = sw[i & 3];
                if (i + 4 < 15) sw[i & 3] = sp[(size_t)(i + 4) * 1024];
            }
            HW uw; uw.v = w;
            aA = dot2acc(d0.h, uw.p[0], aA);
            aA = dot2acc(d1.h, uw.p[1], aA);
            aA = dot2acc(d2.h, uw.p[2], aA);
            aA = dot2acc(d3.h, uw.p[3], aA);
        }
        // W_d slice g: 8 chunks; c chunk k broadcast from lanes 4k..4k+3
        #pragma unroll
        for (int k = 0; k < 8; k++) {
            U32H2 d0, d1, d2, d3;
            d0.u = __builtin_amdgcn_readlane(cp, 4 * k);
            d1.u = __builtin_amdgcn_readlane(cp, 4 * k + 1);
            d2.u = __builtin_amdgcn_readlane(cp, 4 * k + 2);
            d3.u = __builtin_amdgcn_readlane(cp, 4 * k + 3);
            int i = 7 + k;
            half8_t w = sw[i & 3];
            if (i + 4 < 15) sw[i & 3] = sp[(size_t)(i + 4) * 1024];
            HW uw; uw.v = w;
            aD = dot2acc(d0.h, uw.p[0], aD);
            aD = dot2acc(d1.h, uw.p[1], aD);
            aD = dot2acc(d2.h, uw.p[2], aD);
            aD = dot2acc(d3.h, uw.p[3], aD);
        }

        pg[t] = aA + bA + uval;
        pd[t] = aD;
        __syncthreads();

        if (t < 256) {
            float f_ = pg[e], i_ = pg[256 + e], o_ = pg[512 + e], ct = pg[768 + e];
            float ad = pd[e] + pd[256 + e] + pd[512 + e] + pd[768 + e] + wdbt;
            float dly  = db[s];
            float cs   = tanh_f(ad);
            float cadj = (c_reg - cs) + cs * dly;
            float cn   = sigmoid_f(f_) * cadj + sigmoid_f(i_) * tanh_f(ct);
            hn = sigmoid_f(o_) * tanh_f(cn);
            c_reg = cn;
            outb[(size_t)s * H_ + e] = hn;
            h16[e] = (_Float16)hn;
            c16[e] = (_Float16)cn;
        }
        __syncthreads();
    }

    if (t < 256) {
        out[(size_t)B_ * S_ * H_ + (size_t)b * H_ + e] = hn;
        out[(size_t)B_ * S_ * H_ + (size_t)B_ * H_ + (size_t)b * H_ + e] = c_reg;
    }
}

// ---------------------------------------------------------------------------
extern "C" void kernel_launch(void* const* d_in, const int* in_sizes, int n_in,
                              void* d_out, int out_size, void* d_ws, size_t ws_size,
                              hipStream_t stream) {
    const float* inputs     = (const float*)d_in[0];   // [B,S,D]
    const float* timestamps = (const float*)d_in[1];   // [B,S]
    const float* W_all_w    = (const float*)d_in[2];   // [4H,H]
    const float* W_all_b    = (const float*)d_in[3];   // [4H]
    const float* U_all_w    = (const float*)d_in[4];   // [4H,D]
    const float* U_all_b    = (const float*)d_in[5];   // [4H]
    const float* W_d_w      = (const float*)d_in[6];   // [H,H]
    const float* W_d_b      = (const float*)d_in[7];   // [H]
    float* out = (float*)d_out;

    char* p = (char*)d_ws;
    _Float16* u16 = (_Float16*)p;   p += (size_t)B_ * S_ * FH_ * 2;   // 128 MiB
    _Float16* WX  = (_Float16*)p;   p += (size_t)40 * 1024 * 8 * 2;   // 640 KiB
    _Float16* U16 = (_Float16*)p;   p += (size_t)FH_ * D_ * 2;        // 256 KiB
    float*    dec = (float*)p;                                         // 256 KiB

    (void)hipFuncSetAttribute((const void*)scan_kernel,
                              hipFuncAttributeMaxDynamicSharedMemorySize,
                              SMEM_BYTES);

    pack_kernel<<<dim3(928), dim3(256), 0, stream>>>(
        W_all_w, W_d_w, U_all_w, timestamps, WX, U16, dec);
    u_gemm_mfma<<<dim3(1024, 4), dim3(256), 0, stream>>>(
        inputs, U16, U_all_b, u16);
    scan_kernel<<<dim3(B_), dim3(1024), SMEM_BYTES, stream>>>(
        u16, WX, W_all_b, W_d_b, dec, out);
}